// Round 2
// baseline (3165.136 us; speedup 1.0000x reference)
//
#include <hip/hip_runtime.h>
#include <hip/hip_bf16.h>

// GIN 2-layer + BN + softmax pipeline for MI355X. All tensors fp32 on the
// wire (per reference dtypes); edge_index int32. Intermediates fp32 in d_ws.

#define NNODES 50000
#define NEDGES 800000
#define HD 128
#define KOUT 64

// ---------------- scatter-add: agg[dst] += X[src], 32 lanes/edge, 4 feats/lane
__global__ __launch_bounds__(256) void scatter_add_f32(
    const float* __restrict__ X, const int* __restrict__ ei,
    float* __restrict__ agg)
{
    long tid = (long)blockIdx.x * 256 + threadIdx.x;
    int e = (int)(tid >> 5);
    if (e >= NEDGES) return;
    int lane = (int)tid & 31;
    int src = ei[e];
    int dst = ei[NEDGES + e];
    int f = lane * 4;
    float4 v = *(const float4*)(X + (long)src * HD + f);
    float* d = agg + (long)dst * HD + f;
    atomicAdd(d + 0, v.x);
    atomicAdd(d + 1, v.y);
    atomicAdd(d + 2, v.z);
    atomicAdd(d + 3, v.w);
}

// ---------------- GEMM: C[M,128] = op(A) @ W[128,128] + b
// A = (1+eps)*X + AGG (if FUSE_AGG) else X.  16 rows/block, 256 threads,
// thread (c = t&127, g = t>>7) computes 8 rows for column c.
// STATS: per-column sum/sumsq partial reduction -> global atomics (for BN).
template<bool FUSE_AGG, bool RELU, bool STATS>
__global__ __launch_bounds__(256) void gemm128(
    const float* __restrict__ X, const float* __restrict__ AGG,
    const float* __restrict__ eps,
    const float* __restrict__ W, const float* __restrict__ bias,
    float* __restrict__ C, float* __restrict__ out_sum, float* __restrict__ out_sq)
{
    __shared__ float As[16][HD];
    __shared__ float red[2][HD];
    const int t = threadIdx.x;
    const long row0 = (long)blockIdx.x * 16;

    float alpha = 1.f;
    if (FUSE_AGG) alpha = 1.f + eps[0];

    #pragma unroll
    for (int i = 0; i < 8; ++i) {
        int idx = t + i * 256;          // 0..2047
        int r = idx >> 7, cc = idx & 127;
        long gidx = (row0 + r) * HD + cc;
        float v = X[gidx];
        if (FUSE_AGG) v = fmaf(alpha, v, AGG[gidx]);
        As[r][cc] = v;
    }
    __syncthreads();

    const int c = t & 127;
    const int g = t >> 7;               // 0 or 1 -> rows g*8 .. g*8+7
    float acc[8] = {};
    for (int k = 0; k < HD; ++k) {
        float w = W[k * HD + c];
        #pragma unroll
        for (int i = 0; i < 8; ++i)
            acc[i] = fmaf(As[g * 8 + i][k], w, acc[i]);
    }

    float bb = bias[c];
    float lsum = 0.f, lsq = 0.f;
    #pragma unroll
    for (int i = 0; i < 8; ++i) {
        float v = acc[i] + bb;
        if (RELU) v = fmaxf(v, 0.f);
        C[(row0 + g * 8 + i) * HD + c] = v;
        if (STATS) { lsum += v; lsq = fmaf(v, v, lsq); }
    }
    if (STATS) {
        if (g == 0) { red[0][c] = lsum; red[1][c] = lsq; }
        __syncthreads();
        if (g == 1) {
            atomicAdd(&out_sum[c], red[0][c] + lsum);
            atomicAdd(&out_sq[c],  red[1][c] + lsq);
        }
    }
}

// ---------------- BN: fold stats + gamma/beta into per-column scale/shift
__global__ void bn_prep(const float* __restrict__ ssum, const float* __restrict__ ssq,
                        const float* __restrict__ gamma, const float* __restrict__ beta,
                        float* __restrict__ scale, float* __restrict__ shift)
{
    int c = threadIdx.x;
    const float invN = 1.0f / (float)NNODES;
    float m = ssum[c] * invN;
    float var = fmaf(-m, m, ssq[c] * invN);
    float rs = rsqrtf(var + 1e-5f);
    float sc = gamma[c] * rs;
    scale[c] = sc;
    shift[c] = beta[c] - m * sc;
}

// ---------------- apply BN + ReLU in place (float4)
__global__ __launch_bounds__(256) void bn_apply(float* __restrict__ H,
    const float* __restrict__ scale, const float* __restrict__ shift)
{
    long i4 = ((long)blockIdx.x * 256 + threadIdx.x) * 4;
    int c = (int)(i4 & 127);
    float4 v = *(const float4*)(H + i4);
    v.x = fmaxf(fmaf(v.x, scale[c + 0], shift[c + 0]), 0.f);
    v.y = fmaxf(fmaf(v.y, scale[c + 1], shift[c + 1]), 0.f);
    v.z = fmaxf(fmaf(v.z, scale[c + 2], shift[c + 2]), 0.f);
    v.w = fmaxf(fmaf(v.w, scale[c + 3], shift[c + 3]), 0.f);
    *(float4*)(H + i4) = v;
}

// ---------------- final projection (128->64) + temperature softmax
// one wave per row; lane = output class
__global__ __launch_bounds__(256) void out_proj_softmax(
    const float* __restrict__ H, const float* __restrict__ Wout,
    const float* __restrict__ log_tau,
    float* __restrict__ outS, float* __restrict__ outL)
{
    int lane = threadIdx.x & 63;
    int row = blockIdx.x * 4 + (threadIdx.x >> 6);
    const float* h = H + (long)row * HD;
    float acc = 0.f;
    #pragma unroll 4
    for (int k = 0; k < HD; ++k)
        acc = fmaf(h[k], Wout[k * KOUT + lane], acc);

    float inv_tau = __expf(-log_tau[0]);
    float z = acc * inv_tau;
    float m = z;
    #pragma unroll
    for (int o = 32; o > 0; o >>= 1) m = fmaxf(m, __shfl_xor(m, o));
    float e = __expf(z - m);
    float s = e;
    #pragma unroll
    for (int o = 32; o > 0; o >>= 1) s += __shfl_xor(s, o);

    long oi = (long)row * KOUT + lane;
    outS[oi] = e / s;
    outL[oi] = acc;
}

extern "C" void kernel_launch(void* const* d_in, const int* in_sizes, int n_in,
                              void* d_out, int out_size, void* d_ws, size_t ws_size,
                              hipStream_t stream)
{
    const float* x      = (const float*)d_in[0];
    const int*   ei     = (const int*)d_in[1];
    const float* W1a    = (const float*)d_in[2];
    const float* b1a    = (const float*)d_in[3];
    const float* W1b    = (const float*)d_in[4];
    const float* b1b    = (const float*)d_in[5];
    const float* eps1   = (const float*)d_in[6];
    const float* gamma1 = (const float*)d_in[7];
    const float* beta1  = (const float*)d_in[8];
    const float* W2a    = (const float*)d_in[9];
    const float* b2a    = (const float*)d_in[10];
    const float* W2b    = (const float*)d_in[11];
    const float* b2b    = (const float*)d_in[12];
    const float* eps2   = (const float*)d_in[13];
    const float* gamma2 = (const float*)d_in[14];
    const float* beta2  = (const float*)d_in[15];
    const float* Wout   = (const float*)d_in[16];
    const float* ltau   = (const float*)d_in[17];

    const size_t NB = (size_t)NNODES * HD;
    float* B0 = (float*)d_ws;        // agg1, then agg2
    float* B1 = B0 + NB;             // h_lin -> h (in place)
    float* B2 = B1 + NB;             // h_mid
    float* ST = B2 + NB;             // stats
    float* sum1 = ST, *sq1 = ST + 128, *sum2 = ST + 256, *sq2 = ST + 384;
    float* scale1 = ST + 512, *shift1 = ST + 640, *scale2 = ST + 768, *shift2 = ST + 896;

    hipMemsetAsync(B0, 0, NB * sizeof(float), stream);
    hipMemsetAsync(ST, 0, 512 * sizeof(float), stream);

    // ---- layer 1
    scatter_add_f32<<<NEDGES * 32 / 256, 256, 0, stream>>>(x, ei, B0);
    gemm128<true,  true,  false><<<NNODES / 16, 256, 0, stream>>>(
        x, B0, eps1, W1a, b1a, B2, nullptr, nullptr);
    gemm128<false, false, true ><<<NNODES / 16, 256, 0, stream>>>(
        B2, nullptr, nullptr, W1b, b1b, B1, sum1, sq1);
    bn_prep<<<1, 128, 0, stream>>>(sum1, sq1, gamma1, beta1, scale1, shift1);
    bn_apply<<<NNODES * HD / 1024, 256, 0, stream>>>(B1, scale1, shift1);

    // ---- layer 2
    hipMemsetAsync(B0, 0, NB * sizeof(float), stream);
    scatter_add_f32<<<NEDGES * 32 / 256, 256, 0, stream>>>(B1, ei, B0);
    gemm128<true,  true,  false><<<NNODES / 16, 256, 0, stream>>>(
        B1, B0, eps2, W2a, b2a, B2, nullptr, nullptr);
    gemm128<false, false, true ><<<NNODES / 16, 256, 0, stream>>>(
        B2, nullptr, nullptr, W2b, b2b, B1, sum2, sq2);
    bn_prep<<<1, 128, 0, stream>>>(sum2, sq2, gamma2, beta2, scale2, shift2);
    bn_apply<<<NNODES * HD / 1024, 256, 0, stream>>>(B1, scale2, shift2);

    // ---- projection + softmax
    out_proj_softmax<<<NNODES / 4, 256, 0, stream>>>(
        B1, Wout, ltau, (float*)d_out, (float*)d_out + (size_t)NNODES * KOUT);
}

// Round 3
// 675.508 us; speedup vs baseline: 4.6856x; 4.6856x over previous
//
#include <hip/hip_runtime.h>
#include <hip/hip_bf16.h>

// GIN 2-layer + BN + softmax pipeline for MI355X. All tensors fp32; edges int32.
// R3: scatter-add (atomic-latency bound, 2x1344us) replaced by CSR build + gather.

#define NNODES 50000
#define NEDGES 800000
#define HD 128
#define KOUT 64

// ================= CSR build =================
__global__ __launch_bounds__(256) void edge_hist(
    const int* __restrict__ ei, int* __restrict__ deg)
{
    int e = blockIdx.x * 256 + threadIdx.x;
    if (e < NEDGES) atomicAdd(&deg[ei[NEDGES + e]], 1);
}

// inclusive scan of 256-chunks; per-block total to bsum
__global__ __launch_bounds__(256) void scan_a(
    const int* __restrict__ deg, int* __restrict__ incl, int* __restrict__ bsum)
{
    __shared__ int s[256];
    int t = threadIdx.x, idx = blockIdx.x * 256 + t;
    int v = (idx < NNODES) ? deg[idx] : 0;
    s[t] = v; __syncthreads();
    #pragma unroll
    for (int off = 1; off < 256; off <<= 1) {
        int tmp = (t >= off) ? s[t - off] : 0;
        __syncthreads();
        s[t] += tmp;
        __syncthreads();
    }
    if (idx < NNODES) incl[idx] = s[t];
    if (t == 255) bsum[blockIdx.x] = s[255];
}

__global__ __launch_bounds__(256) void scan_b(
    const int* __restrict__ bsum, int* __restrict__ bscan, int nblk)
{
    __shared__ int s[256];
    int t = threadIdx.x;
    s[t] = (t < nblk) ? bsum[t] : 0; __syncthreads();
    #pragma unroll
    for (int off = 1; off < 256; off <<= 1) {
        int tmp = (t >= off) ? s[t - off] : 0;
        __syncthreads();
        s[t] += tmp;
        __syncthreads();
    }
    bscan[t] = s[t];
}

// exclusive offsets: row_start + cursor copy
__global__ __launch_bounds__(256) void scan_c(
    const int* __restrict__ deg, const int* __restrict__ incl,
    const int* __restrict__ bscan,
    int* __restrict__ row_start, int* __restrict__ cur)
{
    int b = blockIdx.x, t = threadIdx.x, idx = b * 256 + t;
    if (idx >= NNODES) return;
    int off = (b > 0) ? bscan[b - 1] : 0;
    int ex = incl[idx] - deg[idx] + off;
    row_start[idx] = ex;
    cur[idx] = ex;
}

__global__ __launch_bounds__(256) void edge_fill(
    const int* __restrict__ ei, int* __restrict__ cur, int* __restrict__ col)
{
    int e = blockIdx.x * 256 + threadIdx.x;
    if (e >= NEDGES) return;
    int pos = atomicAdd(&cur[ei[NEDGES + e]], 1);
    col[pos] = ei[e];
}

// ================= gather aggregation: H0[i] = (1+eps)*X[i] + sum_j X[col[j]]
// 32 lanes/node, float4/lane; cur[] holds end offsets after edge_fill.
__global__ __launch_bounds__(256) void gin_gather(
    const float* __restrict__ X, const int* __restrict__ col,
    const int* __restrict__ rs, const int* __restrict__ re,
    const float* __restrict__ eps, float* __restrict__ H0)
{
    int t = threadIdx.x;
    int node = blockIdx.x * 8 + (t >> 5);
    int lane = t & 31;
    const float4* X4 = (const float4*)X;
    float alpha = 1.f + eps[0];

    float4 xi = X4[(long)node * 32 + lane];
    float4 acc;
    acc.x = alpha * xi.x; acc.y = alpha * xi.y;
    acc.z = alpha * xi.z; acc.w = alpha * xi.w;

    int j = rs[node], end = re[node];
    for (; j + 1 < end; j += 2) {
        int s0 = col[j], s1 = col[j + 1];
        float4 a = X4[(long)s0 * 32 + lane];
        float4 b = X4[(long)s1 * 32 + lane];
        acc.x += a.x + b.x; acc.y += a.y + b.y;
        acc.z += a.z + b.z; acc.w += a.w + b.w;
    }
    if (j < end) {
        float4 a = X4[(long)col[j] * 32 + lane];
        acc.x += a.x; acc.y += a.y; acc.z += a.z; acc.w += a.w;
    }
    ((float4*)H0)[(long)node * 32 + lane] = acc;
}

// ================= legacy scatter (fallback if ws too small) ==========
__global__ __launch_bounds__(256) void scatter_add_f32(
    const float* __restrict__ X, const int* __restrict__ ei,
    float* __restrict__ agg)
{
    long tid = (long)blockIdx.x * 256 + threadIdx.x;
    int e = (int)(tid >> 5);
    if (e >= NEDGES) return;
    int lane = (int)tid & 31;
    int src = ei[e];
    int dst = ei[NEDGES + e];
    int f = lane * 4;
    float4 v = *(const float4*)(X + (long)src * HD + f);
    float* d = agg + (long)dst * HD + f;
    atomicAdd(d + 0, v.x);
    atomicAdd(d + 1, v.y);
    atomicAdd(d + 2, v.z);
    atomicAdd(d + 3, v.w);
}

// ================= GEMM: C[M,128] = op(A) @ W[128,128] + b =================
template<bool FUSE_AGG, bool RELU, bool STATS>
__global__ __launch_bounds__(256) void gemm128(
    const float* __restrict__ X, const float* __restrict__ AGG,
    const float* __restrict__ eps,
    const float* __restrict__ W, const float* __restrict__ bias,
    float* __restrict__ C, float* __restrict__ out_sum, float* __restrict__ out_sq)
{
    __shared__ float As[16][HD];
    __shared__ float red[2][HD];
    const int t = threadIdx.x;
    const long row0 = (long)blockIdx.x * 16;

    float alpha = 1.f;
    if (FUSE_AGG) alpha = 1.f + eps[0];

    #pragma unroll
    for (int i = 0; i < 8; ++i) {
        int idx = t + i * 256;
        int r = idx >> 7, cc = idx & 127;
        long gidx = (row0 + r) * HD + cc;
        float v = X[gidx];
        if (FUSE_AGG) v = fmaf(alpha, v, AGG[gidx]);
        As[r][cc] = v;
    }
    __syncthreads();

    const int c = t & 127;
    const int g = t >> 7;
    float acc[8] = {};
    for (int k = 0; k < HD; ++k) {
        float w = W[k * HD + c];
        #pragma unroll
        for (int i = 0; i < 8; ++i)
            acc[i] = fmaf(As[g * 8 + i][k], w, acc[i]);
    }

    float bb = bias[c];
    float lsum = 0.f, lsq = 0.f;
    #pragma unroll
    for (int i = 0; i < 8; ++i) {
        float v = acc[i] + bb;
        if (RELU) v = fmaxf(v, 0.f);
        C[(row0 + g * 8 + i) * HD + c] = v;
        if (STATS) { lsum += v; lsq = fmaf(v, v, lsq); }
    }
    if (STATS) {
        if (g == 0) { red[0][c] = lsum; red[1][c] = lsq; }
        __syncthreads();
        if (g == 1) {
            atomicAdd(&out_sum[c], red[0][c] + lsum);
            atomicAdd(&out_sq[c],  red[1][c] + lsq);
        }
    }
}

// ================= BN =================
__global__ void bn_prep(const float* __restrict__ ssum, const float* __restrict__ ssq,
                        const float* __restrict__ gamma, const float* __restrict__ beta,
                        float* __restrict__ scale, float* __restrict__ shift)
{
    int c = threadIdx.x;
    const float invN = 1.0f / (float)NNODES;
    float m = ssum[c] * invN;
    float var = fmaf(-m, m, ssq[c] * invN);
    float rs = rsqrtf(var + 1e-5f);
    float sc = gamma[c] * rs;
    scale[c] = sc;
    shift[c] = beta[c] - m * sc;
}

__global__ __launch_bounds__(256) void bn_apply(float* __restrict__ H,
    const float* __restrict__ scale, const float* __restrict__ shift)
{
    long i4 = ((long)blockIdx.x * 256 + threadIdx.x) * 4;
    int c = (int)(i4 & 127);
    float4 v = *(const float4*)(H + i4);
    v.x = fmaxf(fmaf(v.x, scale[c + 0], shift[c + 0]), 0.f);
    v.y = fmaxf(fmaf(v.y, scale[c + 1], shift[c + 1]), 0.f);
    v.z = fmaxf(fmaf(v.z, scale[c + 2], shift[c + 2]), 0.f);
    v.w = fmaxf(fmaf(v.w, scale[c + 3], shift[c + 3]), 0.f);
    *(float4*)(H + i4) = v;
}

// ================= projection + softmax =================
__global__ __launch_bounds__(256) void out_proj_softmax(
    const float* __restrict__ H, const float* __restrict__ Wout,
    const float* __restrict__ log_tau,
    float* __restrict__ outS, float* __restrict__ outL)
{
    int lane = threadIdx.x & 63;
    int row = blockIdx.x * 4 + (threadIdx.x >> 6);
    const float* h = H + (long)row * HD;
    float acc = 0.f;
    #pragma unroll 4
    for (int k = 0; k < HD; ++k)
        acc = fmaf(h[k], Wout[k * KOUT + lane], acc);

    float inv_tau = __expf(-log_tau[0]);
    float z = acc * inv_tau;
    float m = z;
    #pragma unroll
    for (int o = 32; o > 0; o >>= 1) m = fmaxf(m, __shfl_xor(m, o));
    float e = __expf(z - m);
    float s = e;
    #pragma unroll
    for (int o = 32; o > 0; o >>= 1) s += __shfl_xor(s, o);

    long oi = (long)row * KOUT + lane;
    outS[oi] = e / s;
    outL[oi] = acc;
}

extern "C" void kernel_launch(void* const* d_in, const int* in_sizes, int n_in,
                              void* d_out, int out_size, void* d_ws, size_t ws_size,
                              hipStream_t stream)
{
    const float* x      = (const float*)d_in[0];
    const int*   ei     = (const int*)d_in[1];
    const float* W1a    = (const float*)d_in[2];
    const float* b1a    = (const float*)d_in[3];
    const float* W1b    = (const float*)d_in[4];
    const float* b1b    = (const float*)d_in[5];
    const float* eps1   = (const float*)d_in[6];
    const float* gamma1 = (const float*)d_in[7];
    const float* beta1  = (const float*)d_in[8];
    const float* W2a    = (const float*)d_in[9];
    const float* b2a    = (const float*)d_in[10];
    const float* W2b    = (const float*)d_in[11];
    const float* b2b    = (const float*)d_in[12];
    const float* eps2   = (const float*)d_in[13];
    const float* gamma2 = (const float*)d_in[14];
    const float* beta2  = (const float*)d_in[15];
    const float* Wout   = (const float*)d_in[16];
    const float* ltau   = (const float*)d_in[17];

    const size_t NB = (size_t)NNODES * HD;
    float* B0 = (float*)d_ws;        // H0 (gather out) / agg in fallback
    float* B1 = B0 + NB;             // h
    float* B2 = B1 + NB;             // mid
    float* ST = B2 + NB;             // stats (1024 floats)
    float* sum1 = ST, *sq1 = ST + 128, *sum2 = ST + 256, *sq2 = ST + 384;
    float* scale1 = ST + 512, *shift1 = ST + 640, *scale2 = ST + 768, *shift2 = ST + 896;

    int* I0        = (int*)(ST + 1024);
    int* deg       = I0;
    int* incl      = I0 + 50048;
    int* row_start = I0 + 2 * 50048;
    int* cur       = I0 + 3 * 50048;
    int* bsum      = I0 + 4 * 50048;
    int* bscan     = bsum + 256;
    int* col       = bscan + 256;     // NEDGES ints

    const size_t needed = ((size_t)(ST + 1024) - (size_t)d_ws)
                        + (4 * 50048 + 512 + NEDGES) * sizeof(int);
    const bool use_csr = ws_size >= needed;

    const int SCAN_BLKS = (NNODES + 255) / 256;   // 196

    hipMemsetAsync(ST, 0, 512 * sizeof(float), stream);

    if (use_csr) {
        hipMemsetAsync(deg, 0, NNODES * sizeof(int), stream);
        edge_hist<<<(NEDGES + 255) / 256, 256, 0, stream>>>(ei, deg);
        scan_a<<<SCAN_BLKS, 256, 0, stream>>>(deg, incl, bsum);
        scan_b<<<1, 256, 0, stream>>>(bsum, bscan, SCAN_BLKS);
        scan_c<<<SCAN_BLKS, 256, 0, stream>>>(deg, incl, bscan, row_start, cur);
        edge_fill<<<(NEDGES + 255) / 256, 256, 0, stream>>>(ei, cur, col);

        // ---- layer 1
        gin_gather<<<NNODES / 8, 256, 0, stream>>>(x, col, row_start, cur, eps1, B0);
        gemm128<false, true,  false><<<NNODES / 16, 256, 0, stream>>>(
            B0, nullptr, nullptr, W1a, b1a, B2, nullptr, nullptr);
        gemm128<false, false, true ><<<NNODES / 16, 256, 0, stream>>>(
            B2, nullptr, nullptr, W1b, b1b, B1, sum1, sq1);
        bn_prep<<<1, 128, 0, stream>>>(sum1, sq1, gamma1, beta1, scale1, shift1);
        bn_apply<<<NNODES * HD / 1024, 256, 0, stream>>>(B1, scale1, shift1);

        // ---- layer 2
        gin_gather<<<NNODES / 8, 256, 0, stream>>>(B1, col, row_start, cur, eps2, B0);
        gemm128<false, true,  false><<<NNODES / 16, 256, 0, stream>>>(
            B0, nullptr, nullptr, W2a, b2a, B2, nullptr, nullptr);
        gemm128<false, false, true ><<<NNODES / 16, 256, 0, stream>>>(
            B2, nullptr, nullptr, W2b, b2b, B1, sum2, sq2);
        bn_prep<<<1, 128, 0, stream>>>(sum2, sq2, gamma2, beta2, scale2, shift2);
        bn_apply<<<NNODES * HD / 1024, 256, 0, stream>>>(B1, scale2, shift2);
    } else {
        // fallback: atomic scatter path (known-correct R2 structure)
        hipMemsetAsync(B0, 0, NB * sizeof(float), stream);
        scatter_add_f32<<<NEDGES * 32 / 256, 256, 0, stream>>>(x, ei, B0);
        gemm128<true,  true,  false><<<NNODES / 16, 256, 0, stream>>>(
            x, B0, eps1, W1a, b1a, B2, nullptr, nullptr);
        gemm128<false, false, true ><<<NNODES / 16, 256, 0, stream>>>(
            B2, nullptr, nullptr, W1b, b1b, B1, sum1, sq1);
        bn_prep<<<1, 128, 0, stream>>>(sum1, sq1, gamma1, beta1, scale1, shift1);
        bn_apply<<<NNODES * HD / 1024, 256, 0, stream>>>(B1, scale1, shift1);

        hipMemsetAsync(B0, 0, NB * sizeof(float), stream);
        scatter_add_f32<<<NEDGES * 32 / 256, 256, 0, stream>>>(B1, ei, B0);
        gemm128<true,  true,  false><<<NNODES / 16, 256, 0, stream>>>(
            B1, B0, eps2, W2a, b2a, B2, nullptr, nullptr);
        gemm128<false, false, true ><<<NNODES / 16, 256, 0, stream>>>(
            B2, nullptr, nullptr, W2b, b2b, B1, sum2, sq2);
        bn_prep<<<1, 128, 0, stream>>>(sum2, sq2, gamma2, beta2, scale2, shift2);
        bn_apply<<<NNODES * HD / 1024, 256, 0, stream>>>(B1, scale2, shift2);
    }

    // ---- projection + softmax
    out_proj_softmax<<<NNODES / 4, 256, 0, stream>>>(
        B1, Wout, ltau, (float*)d_out, (float*)d_out + (size_t)NNODES * KOUT);
}

// Round 4
// 590.955 us; speedup vs baseline: 5.3560x; 1.1431x over previous
//
#include <hip/hip_runtime.h>
#include <hip/hip_bf16.h>

// GIN 2-layer + BN + softmax pipeline for MI355X. All tensors fp32; edges int32.
// R4: latency-bound gemm/out_proj restructured (As^T in LDS + b128 broadcast
// reads + k-unroll); BN+ReLU fused into gather (L1) and out_proj staging (L2).

#define NNODES 50000
#define NEDGES 800000
#define HD 128
#define KOUT 64

// ================= CSR build =================
__global__ __launch_bounds__(256) void edge_hist(
    const int* __restrict__ ei, int* __restrict__ deg)
{
    int e = blockIdx.x * 256 + threadIdx.x;
    if (e < NEDGES) atomicAdd(&deg[ei[NEDGES + e]], 1);
}

__global__ __launch_bounds__(256) void scan_a(
    const int* __restrict__ deg, int* __restrict__ incl, int* __restrict__ bsum)
{
    __shared__ int s[256];
    int t = threadIdx.x, idx = blockIdx.x * 256 + t;
    int v = (idx < NNODES) ? deg[idx] : 0;
    s[t] = v; __syncthreads();
    #pragma unroll
    for (int off = 1; off < 256; off <<= 1) {
        int tmp = (t >= off) ? s[t - off] : 0;
        __syncthreads();
        s[t] += tmp;
        __syncthreads();
    }
    if (idx < NNODES) incl[idx] = s[t];
    if (t == 255) bsum[blockIdx.x] = s[255];
}

__global__ __launch_bounds__(256) void scan_b(
    const int* __restrict__ bsum, int* __restrict__ bscan, int nblk)
{
    __shared__ int s[256];
    int t = threadIdx.x;
    s[t] = (t < nblk) ? bsum[t] : 0; __syncthreads();
    #pragma unroll
    for (int off = 1; off < 256; off <<= 1) {
        int tmp = (t >= off) ? s[t - off] : 0;
        __syncthreads();
        s[t] += tmp;
        __syncthreads();
    }
    bscan[t] = s[t];
}

__global__ __launch_bounds__(256) void scan_c(
    const int* __restrict__ deg, const int* __restrict__ incl,
    const int* __restrict__ bscan,
    int* __restrict__ row_start, int* __restrict__ cur)
{
    int b = blockIdx.x, t = threadIdx.x, idx = b * 256 + t;
    if (idx >= NNODES) return;
    int off = (b > 0) ? bscan[b - 1] : 0;
    int ex = incl[idx] - deg[idx] + off;
    row_start[idx] = ex;
    cur[idx] = ex;
}

__global__ __launch_bounds__(256) void edge_fill(
    const int* __restrict__ ei, int* __restrict__ cur, int* __restrict__ col)
{
    int e = blockIdx.x * 256 + threadIdx.x;
    if (e >= NEDGES) return;
    int pos = atomicAdd(&cur[ei[NEDGES + e]], 1);
    col[pos] = ei[e];
}

// ========== gather: H0[i] = (1+eps)*f(X[i]) + sum_j f(X[col[j]])
// f = BN-scale/shift + ReLU when BN=true (folds previous layer's bn_apply).
template<bool BN>
__global__ __launch_bounds__(256) void gin_gather(
    const float* __restrict__ X, const int* __restrict__ col,
    const int* __restrict__ rs, const int* __restrict__ re,
    const float* __restrict__ eps,
    const float* __restrict__ scale, const float* __restrict__ shift,
    float* __restrict__ H0)
{
    int t = threadIdx.x;
    int node = blockIdx.x * 8 + (t >> 5);
    int lane = t & 31;
    const float4* X4 = (const float4*)X;
    float alpha = 1.f + eps[0];

    float4 sc, sh;
    if (BN) { sc = ((const float4*)scale)[lane]; sh = ((const float4*)shift)[lane]; }

    float4 xi = X4[(long)node * 32 + lane];
    if (BN) {
        xi.x = fmaxf(fmaf(xi.x, sc.x, sh.x), 0.f);
        xi.y = fmaxf(fmaf(xi.y, sc.y, sh.y), 0.f);
        xi.z = fmaxf(fmaf(xi.z, sc.z, sh.z), 0.f);
        xi.w = fmaxf(fmaf(xi.w, sc.w, sh.w), 0.f);
    }
    float4 acc;
    acc.x = alpha * xi.x; acc.y = alpha * xi.y;
    acc.z = alpha * xi.z; acc.w = alpha * xi.w;

    int j = rs[node], end = re[node];
    for (; j + 1 < end; j += 2) {
        int s0 = col[j], s1 = col[j + 1];
        float4 a = X4[(long)s0 * 32 + lane];
        float4 b = X4[(long)s1 * 32 + lane];
        if (BN) {
            a.x = fmaxf(fmaf(a.x, sc.x, sh.x), 0.f);
            a.y = fmaxf(fmaf(a.y, sc.y, sh.y), 0.f);
            a.z = fmaxf(fmaf(a.z, sc.z, sh.z), 0.f);
            a.w = fmaxf(fmaf(a.w, sc.w, sh.w), 0.f);
            b.x = fmaxf(fmaf(b.x, sc.x, sh.x), 0.f);
            b.y = fmaxf(fmaf(b.y, sc.y, sh.y), 0.f);
            b.z = fmaxf(fmaf(b.z, sc.z, sh.z), 0.f);
            b.w = fmaxf(fmaf(b.w, sc.w, sh.w), 0.f);
        }
        acc.x += a.x + b.x; acc.y += a.y + b.y;
        acc.z += a.z + b.z; acc.w += a.w + b.w;
    }
    if (j < end) {
        float4 a = X4[(long)col[j] * 32 + lane];
        if (BN) {
            a.x = fmaxf(fmaf(a.x, sc.x, sh.x), 0.f);
            a.y = fmaxf(fmaf(a.y, sc.y, sh.y), 0.f);
            a.z = fmaxf(fmaf(a.z, sc.z, sh.z), 0.f);
            a.w = fmaxf(fmaf(a.w, sc.w, sh.w), 0.f);
        }
        acc.x += a.x; acc.y += a.y; acc.z += a.z; acc.w += a.w;
    }
    ((float4*)H0)[(long)node * 32 + lane] = acc;
}

// ========== GEMM v2: C[M,128] = A @ W[128,128] + b
// 16 rows/block; A-tile TRANSPOSED in LDS (As[k][r], pad 20 -> b128 reads).
// thread (c=t&127, g=t>>7) -> 8 rows of column c. k-loop unrolled 4.
template<bool RELU, bool STATS>
__global__ __launch_bounds__(256) void gemm128(
    const float* __restrict__ X,
    const float* __restrict__ W, const float* __restrict__ bias,
    float* __restrict__ C, float* __restrict__ out_sum, float* __restrict__ out_sq)
{
    __shared__ float As[HD][20];   // [k][r], 80B rows (16B aligned), benign write conflicts
    __shared__ float red[2][HD];
    const int t = threadIdx.x;
    const long row0 = (long)blockIdx.x * 16;

    #pragma unroll
    for (int i = 0; i < 8; ++i) {
        int idx = t + i * 256;
        int r = idx >> 7, cc = idx & 127;
        As[cc][r] = X[(row0 + r) * HD + cc];
    }
    __syncthreads();

    const int c = t & 127;
    const int g = t >> 7;
    float acc[8] = {};
    #pragma unroll 4
    for (int k = 0; k < HD; ++k) {
        float w = W[k * HD + c];
        const float4* ap = (const float4*)&As[k][g * 8];
        float4 a0 = ap[0], a1 = ap[1];
        acc[0] = fmaf(a0.x, w, acc[0]);
        acc[1] = fmaf(a0.y, w, acc[1]);
        acc[2] = fmaf(a0.z, w, acc[2]);
        acc[3] = fmaf(a0.w, w, acc[3]);
        acc[4] = fmaf(a1.x, w, acc[4]);
        acc[5] = fmaf(a1.y, w, acc[5]);
        acc[6] = fmaf(a1.z, w, acc[6]);
        acc[7] = fmaf(a1.w, w, acc[7]);
    }

    float bb = bias[c];
    float lsum = 0.f, lsq = 0.f;
    #pragma unroll
    for (int i = 0; i < 8; ++i) {
        float v = acc[i] + bb;
        if (RELU) v = fmaxf(v, 0.f);
        C[(row0 + g * 8 + i) * HD + c] = v;
        if (STATS) { lsum += v; lsq = fmaf(v, v, lsq); }
    }
    if (STATS) {
        if (g == 0) { red[0][c] = lsum; red[1][c] = lsq; }
        __syncthreads();
        if (g == 1) {
            atomicAdd(&out_sum[c], red[0][c] + lsum);
            atomicAdd(&out_sq[c],  red[1][c] + lsq);
        }
    }
}

// ================= BN fold =================
__global__ void bn_prep(const float* __restrict__ ssum, const float* __restrict__ ssq,
                        const float* __restrict__ gamma, const float* __restrict__ beta,
                        float* __restrict__ scale, float* __restrict__ shift)
{
    int c = threadIdx.x;
    const float invN = 1.0f / (float)NNODES;
    float m = ssum[c] * invN;
    float var = fmaf(-m, m, ssq[c] * invN);
    float rs = rsqrtf(var + 1e-5f);
    float sc = gamma[c] * rs;
    scale[c] = sc;
    shift[c] = beta[c] - m * sc;
}

// ========== projection + softmax, BN2+ReLU fused on load ==========
// 16 rows/block; As[k][r] transposed; thread (c=t&63, g=t>>6) -> rows g*4..g*4+3.
// wave g holds row's 64 classes across its lanes -> shuffle softmax.
__global__ __launch_bounds__(256) void out_proj_softmax(
    const float* __restrict__ H, const float* __restrict__ Wout,
    const float* __restrict__ scale, const float* __restrict__ shift,
    const float* __restrict__ log_tau,
    float* __restrict__ outS, float* __restrict__ outL)
{
    __shared__ float As[HD][20];
    const int t = threadIdx.x;
    const long row0 = (long)blockIdx.x * 16;

    #pragma unroll
    for (int i = 0; i < 8; ++i) {
        int idx = t + i * 256;
        int r = idx >> 7, cc = idx & 127;
        float v = H[(row0 + r) * HD + cc];
        As[cc][r] = fmaxf(fmaf(v, scale[cc], shift[cc]), 0.f);
    }
    __syncthreads();

    const int c = t & 63;
    const int g = t >> 6;
    float acc[4] = {};
    #pragma unroll 4
    for (int k = 0; k < HD; ++k) {
        float w = Wout[k * KOUT + c];
        float4 a = *(const float4*)&As[k][g * 4];
        acc[0] = fmaf(a.x, w, acc[0]);
        acc[1] = fmaf(a.y, w, acc[1]);
        acc[2] = fmaf(a.z, w, acc[2]);
        acc[3] = fmaf(a.w, w, acc[3]);
    }

    float inv_tau = __expf(-log_tau[0]);
    #pragma unroll
    for (int i = 0; i < 4; ++i) {
        float z = acc[i] * inv_tau;
        float m = z;
        #pragma unroll
        for (int o = 32; o > 0; o >>= 1) m = fmaxf(m, __shfl_xor(m, o));
        float e = __expf(z - m);
        float s = e;
        #pragma unroll
        for (int o = 32; o > 0; o >>= 1) s += __shfl_xor(s, o);
        long oi = (row0 + g * 4 + i) * KOUT + c;
        outS[oi] = e / s;
        outL[oi] = acc[i];
    }
}

extern "C" void kernel_launch(void* const* d_in, const int* in_sizes, int n_in,
                              void* d_out, int out_size, void* d_ws, size_t ws_size,
                              hipStream_t stream)
{
    const float* x      = (const float*)d_in[0];
    const int*   ei     = (const int*)d_in[1];
    const float* W1a    = (const float*)d_in[2];
    const float* b1a    = (const float*)d_in[3];
    const float* W1b    = (const float*)d_in[4];
    const float* b1b    = (const float*)d_in[5];
    const float* eps1   = (const float*)d_in[6];
    const float* gamma1 = (const float*)d_in[7];
    const float* beta1  = (const float*)d_in[8];
    const float* W2a    = (const float*)d_in[9];
    const float* b2a    = (const float*)d_in[10];
    const float* W2b    = (const float*)d_in[11];
    const float* b2b    = (const float*)d_in[12];
    const float* eps2   = (const float*)d_in[13];
    const float* gamma2 = (const float*)d_in[14];
    const float* beta2  = (const float*)d_in[15];
    const float* Wout   = (const float*)d_in[16];
    const float* ltau   = (const float*)d_in[17];

    const size_t NB = (size_t)NNODES * HD;
    float* B0 = (float*)d_ws;        // gather output H0
    float* B1 = B0 + NB;             // pre-BN hidden h
    float* B2 = B1 + NB;             // MLP mid
    float* ST = B2 + NB;             // stats (1024 floats)
    float* sum1 = ST, *sq1 = ST + 128, *sum2 = ST + 256, *sq2 = ST + 384;
    float* scale1 = ST + 512, *shift1 = ST + 640, *scale2 = ST + 768, *shift2 = ST + 896;

    int* I0        = (int*)(ST + 1024);
    int* deg       = I0;
    int* incl      = I0 + 50048;
    int* row_start = I0 + 2 * 50048;
    int* cur       = I0 + 3 * 50048;
    int* bsum      = I0 + 4 * 50048;
    int* bscan     = bsum + 256;
    int* col       = bscan + 256;     // NEDGES ints

    const int SCAN_BLKS = (NNODES + 255) / 256;   // 196

    hipMemsetAsync(ST, 0, 512 * sizeof(float), stream);
    hipMemsetAsync(deg, 0, NNODES * sizeof(int), stream);
    edge_hist<<<(NEDGES + 255) / 256, 256, 0, stream>>>(ei, deg);
    scan_a<<<SCAN_BLKS, 256, 0, stream>>>(deg, incl, bsum);
    scan_b<<<1, 256, 0, stream>>>(bsum, bscan, SCAN_BLKS);
    scan_c<<<SCAN_BLKS, 256, 0, stream>>>(deg, incl, bscan, row_start, cur);
    edge_fill<<<(NEDGES + 255) / 256, 256, 0, stream>>>(ei, cur, col);

    // ---- layer 1
    gin_gather<false><<<NNODES / 8, 256, 0, stream>>>(
        x, col, row_start, cur, eps1, nullptr, nullptr, B0);
    gemm128<true,  false><<<NNODES / 16, 256, 0, stream>>>(
        B0, W1a, b1a, B2, nullptr, nullptr);
    gemm128<false, true ><<<NNODES / 16, 256, 0, stream>>>(
        B2, W1b, b1b, B1, sum1, sq1);
    bn_prep<<<1, 128, 0, stream>>>(sum1, sq1, gamma1, beta1, scale1, shift1);

    // ---- layer 2 (BN1+ReLU fused into gather reads)
    gin_gather<true><<<NNODES / 8, 256, 0, stream>>>(
        B1, col, row_start, cur, eps2, scale1, shift1, B0);
    gemm128<true,  false><<<NNODES / 16, 256, 0, stream>>>(
        B0, W2a, b2a, B2, nullptr, nullptr);
    gemm128<false, true ><<<NNODES / 16, 256, 0, stream>>>(
        B2, W2b, b2b, B1, sum2, sq2);
    bn_prep<<<1, 128, 0, stream>>>(sum2, sq2, gamma2, beta2, scale2, shift2);

    // ---- projection + softmax (BN2+ReLU fused on load)
    out_proj_softmax<<<NNODES / 16, 256, 0, stream>>>(
        B1, Wout, scale2, shift2, ltau,
        (float*)d_out, (float*)d_out + (size_t)NNODES * KOUT);
}

// Round 5
// 514.339 us; speedup vs baseline: 6.1538x; 1.1490x over previous
//
#include <hip/hip_runtime.h>
#include <hip/hip_bf16.h>

// GIN 2-layer + BN + softmax pipeline for MI355X. All tensors fp32; edges int32.
// R5: gemm128 register-blocked 8x4 outputs/thread (64-row tiles, row-major LDS,
// conflict-free staging) -> VALU-bound instead of load-issue-bound.

#define NNODES 50000
#define NEDGES 800000
#define HD 128
#define KOUT 64

// ================= CSR build =================
__global__ __launch_bounds__(256) void edge_hist(
    const int* __restrict__ ei, int* __restrict__ deg)
{
    int e = blockIdx.x * 256 + threadIdx.x;
    if (e < NEDGES) atomicAdd(&deg[ei[NEDGES + e]], 1);
}

__global__ __launch_bounds__(256) void scan_a(
    const int* __restrict__ deg, int* __restrict__ incl, int* __restrict__ bsum)
{
    __shared__ int s[256];
    int t = threadIdx.x, idx = blockIdx.x * 256 + t;
    int v = (idx < NNODES) ? deg[idx] : 0;
    s[t] = v; __syncthreads();
    #pragma unroll
    for (int off = 1; off < 256; off <<= 1) {
        int tmp = (t >= off) ? s[t - off] : 0;
        __syncthreads();
        s[t] += tmp;
        __syncthreads();
    }
    if (idx < NNODES) incl[idx] = s[t];
    if (t == 255) bsum[blockIdx.x] = s[255];
}

__global__ __launch_bounds__(256) void scan_b(
    const int* __restrict__ bsum, int* __restrict__ bscan, int nblk)
{
    __shared__ int s[256];
    int t = threadIdx.x;
    s[t] = (t < nblk) ? bsum[t] : 0; __syncthreads();
    #pragma unroll
    for (int off = 1; off < 256; off <<= 1) {
        int tmp = (t >= off) ? s[t - off] : 0;
        __syncthreads();
        s[t] += tmp;
        __syncthreads();
    }
    bscan[t] = s[t];
}

__global__ __launch_bounds__(256) void scan_c(
    const int* __restrict__ deg, const int* __restrict__ incl,
    const int* __restrict__ bscan,
    int* __restrict__ row_start, int* __restrict__ cur)
{
    int b = blockIdx.x, t = threadIdx.x, idx = b * 256 + t;
    if (idx >= NNODES) return;
    int off = (b > 0) ? bscan[b - 1] : 0;
    int ex = incl[idx] - deg[idx] + off;
    row_start[idx] = ex;
    cur[idx] = ex;
}

__global__ __launch_bounds__(256) void edge_fill(
    const int* __restrict__ ei, int* __restrict__ cur, int* __restrict__ col)
{
    int e = blockIdx.x * 256 + threadIdx.x;
    if (e >= NEDGES) return;
    int pos = atomicAdd(&cur[ei[NEDGES + e]], 1);
    col[pos] = ei[e];
}

// ========== gather: H0[i] = (1+eps)*f(X[i]) + sum_j f(X[col[j]])
// f = BN-scale/shift + ReLU when BN=true.
template<bool BN>
__global__ __launch_bounds__(256) void gin_gather(
    const float* __restrict__ X, const int* __restrict__ col,
    const int* __restrict__ rs, const int* __restrict__ re,
    const float* __restrict__ eps,
    const float* __restrict__ scale, const float* __restrict__ shift,
    float* __restrict__ H0)
{
    int t = threadIdx.x;
    int node = blockIdx.x * 8 + (t >> 5);
    int lane = t & 31;
    const float4* X4 = (const float4*)X;
    float alpha = 1.f + eps[0];

    float4 sc, sh;
    if (BN) { sc = ((const float4*)scale)[lane]; sh = ((const float4*)shift)[lane]; }

    float4 xi = X4[(long)node * 32 + lane];
    if (BN) {
        xi.x = fmaxf(fmaf(xi.x, sc.x, sh.x), 0.f);
        xi.y = fmaxf(fmaf(xi.y, sc.y, sh.y), 0.f);
        xi.z = fmaxf(fmaf(xi.z, sc.z, sh.z), 0.f);
        xi.w = fmaxf(fmaf(xi.w, sc.w, sh.w), 0.f);
    }
    float4 acc;
    acc.x = alpha * xi.x; acc.y = alpha * xi.y;
    acc.z = alpha * xi.z; acc.w = alpha * xi.w;

    int j = rs[node], end = re[node];
    for (; j + 1 < end; j += 2) {
        int s0 = col[j], s1 = col[j + 1];
        float4 a = X4[(long)s0 * 32 + lane];
        float4 b = X4[(long)s1 * 32 + lane];
        if (BN) {
            a.x = fmaxf(fmaf(a.x, sc.x, sh.x), 0.f);
            a.y = fmaxf(fmaf(a.y, sc.y, sh.y), 0.f);
            a.z = fmaxf(fmaf(a.z, sc.z, sh.z), 0.f);
            a.w = fmaxf(fmaf(a.w, sc.w, sh.w), 0.f);
            b.x = fmaxf(fmaf(b.x, sc.x, sh.x), 0.f);
            b.y = fmaxf(fmaf(b.y, sc.y, sh.y), 0.f);
            b.z = fmaxf(fmaf(b.z, sc.z, sh.z), 0.f);
            b.w = fmaxf(fmaf(b.w, sc.w, sh.w), 0.f);
        }
        acc.x += a.x + b.x; acc.y += a.y + b.y;
        acc.z += a.z + b.z; acc.w += a.w + b.w;
    }
    if (j < end) {
        float4 a = X4[(long)col[j] * 32 + lane];
        if (BN) {
            a.x = fmaxf(fmaf(a.x, sc.x, sh.x), 0.f);
            a.y = fmaxf(fmaf(a.y, sc.y, sh.y), 0.f);
            a.z = fmaxf(fmaf(a.z, sc.z, sh.z), 0.f);
            a.w = fmaxf(fmaf(a.w, sc.w, sh.w), 0.f);
        }
        acc.x += a.x; acc.y += a.y; acc.z += a.z; acc.w += a.w;
    }
    ((float4*)H0)[(long)node * 32 + lane] = acc;
}

// ========== GEMM v3: C[M,128] = A @ W[128,128] + b
// 64 rows/block, 256 threads, each thread 8 rows x 4 cols.
// A-tile row-major in LDS (pad 132 -> staging conflict-free); A k-reads are
// wave-broadcast (2 addrs); W float4 loads L1/L2-resident, coalesced.
template<bool RELU, bool STATS>
__global__ __launch_bounds__(256) void gemm128(
    const float* __restrict__ X,
    const float* __restrict__ W, const float* __restrict__ bias,
    float* __restrict__ C, float* __restrict__ out_sum, float* __restrict__ out_sq)
{
    __shared__ float As[64][132];
    const int t = threadIdx.x;
    const int row0 = blockIdx.x * 64;

    #pragma unroll
    for (int i = 0; i < 8; ++i) {
        int idx = t + i * 256;          // float4 slot 0..2047
        int r = idx >> 5, c4 = idx & 31;
        float4 v = make_float4(0.f, 0.f, 0.f, 0.f);
        if (row0 + r < NNODES)
            v = *(const float4*)(X + (long)(row0 + r) * HD + c4 * 4);
        *(float4*)&As[r][c4 * 4] = v;
    }
    __syncthreads();

    const int c0 = (t & 31) * 4;
    const int r0 = (t >> 5) * 8;
    float acc[8][4] = {};
    #pragma unroll 4
    for (int k = 0; k < HD; ++k) {
        float4 w = *(const float4*)(W + k * HD + c0);
        #pragma unroll
        for (int j = 0; j < 8; ++j) {
            float a = As[r0 + j][k];
            acc[j][0] = fmaf(a, w.x, acc[j][0]);
            acc[j][1] = fmaf(a, w.y, acc[j][1]);
            acc[j][2] = fmaf(a, w.z, acc[j][2]);
            acc[j][3] = fmaf(a, w.w, acc[j][3]);
        }
    }

    float4 bb = *(const float4*)(bias + c0);
    float lsum[4] = {}, lsq[4] = {};
    #pragma unroll
    for (int j = 0; j < 8; ++j) {
        int row = row0 + r0 + j;
        float4 v;
        v.x = acc[j][0] + bb.x; v.y = acc[j][1] + bb.y;
        v.z = acc[j][2] + bb.z; v.w = acc[j][3] + bb.w;
        if (RELU) {
            v.x = fmaxf(v.x, 0.f); v.y = fmaxf(v.y, 0.f);
            v.z = fmaxf(v.z, 0.f); v.w = fmaxf(v.w, 0.f);
        }
        if (row < NNODES) {
            *(float4*)(C + (long)row * HD + c0) = v;
            if (STATS) {
                lsum[0] += v.x; lsum[1] += v.y; lsum[2] += v.z; lsum[3] += v.w;
                lsq[0] = fmaf(v.x, v.x, lsq[0]);
                lsq[1] = fmaf(v.y, v.y, lsq[1]);
                lsq[2] = fmaf(v.z, v.z, lsq[2]);
                lsq[3] = fmaf(v.w, v.w, lsq[3]);
            }
        }
    }
    if (STATS) {
        __shared__ float redS[8][128];
        __shared__ float redQ[8][128];
        const int rg = t >> 5;
        #pragma unroll
        for (int j = 0; j < 4; ++j) {
            redS[rg][c0 + j] = lsum[j];
            redQ[rg][c0 + j] = lsq[j];
        }
        __syncthreads();
        if (t < 128) {
            float s = 0.f, q = 0.f;
            #pragma unroll
            for (int g = 0; g < 8; ++g) { s += redS[g][t]; q += redQ[g][t]; }
            atomicAdd(&out_sum[t], s);
            atomicAdd(&out_sq[t],  q);
        }
    }
}

// ================= BN fold =================
__global__ void bn_prep(const float* __restrict__ ssum, const float* __restrict__ ssq,
                        const float* __restrict__ gamma, const float* __restrict__ beta,
                        float* __restrict__ scale, float* __restrict__ shift)
{
    int c = threadIdx.x;
    const float invN = 1.0f / (float)NNODES;
    float m = ssum[c] * invN;
    float var = fmaf(-m, m, ssq[c] * invN);
    float rs = rsqrtf(var + 1e-5f);
    float sc = gamma[c] * rs;
    scale[c] = sc;
    shift[c] = beta[c] - m * sc;
}

// ========== projection + softmax, BN2+ReLU fused on load ==========
__global__ __launch_bounds__(256) void out_proj_softmax(
    const float* __restrict__ H, const float* __restrict__ Wout,
    const float* __restrict__ scale, const float* __restrict__ shift,
    const float* __restrict__ log_tau,
    float* __restrict__ outS, float* __restrict__ outL)
{
    __shared__ float As[HD][20];
    const int t = threadIdx.x;
    const long row0 = (long)blockIdx.x * 16;

    #pragma unroll
    for (int i = 0; i < 8; ++i) {
        int idx = t + i * 256;
        int r = idx >> 7, cc = idx & 127;
        float v = H[(row0 + r) * HD + cc];
        As[cc][r] = fmaxf(fmaf(v, scale[cc], shift[cc]), 0.f);
    }
    __syncthreads();

    const int c = t & 63;
    const int g = t >> 6;
    float acc[4] = {};
    #pragma unroll 4
    for (int k = 0; k < HD; ++k) {
        float w = Wout[k * KOUT + c];
        float4 a = *(const float4*)&As[k][g * 4];
        acc[0] = fmaf(a.x, w, acc[0]);
        acc[1] = fmaf(a.y, w, acc[1]);
        acc[2] = fmaf(a.z, w, acc[2]);
        acc[3] = fmaf(a.w, w, acc[3]);
    }

    float inv_tau = __expf(-log_tau[0]);
    #pragma unroll
    for (int i = 0; i < 4; ++i) {
        float z = acc[i] * inv_tau;
        float m = z;
        #pragma unroll
        for (int o = 32; o > 0; o >>= 1) m = fmaxf(m, __shfl_xor(m, o));
        float e = __expf(z - m);
        float s = e;
        #pragma unroll
        for (int o = 32; o > 0; o >>= 1) s += __shfl_xor(s, o);
        long oi = (row0 + g * 4 + i) * KOUT + c;
        outS[oi] = e / s;
        outL[oi] = acc[i];
    }
}

extern "C" void kernel_launch(void* const* d_in, const int* in_sizes, int n_in,
                              void* d_out, int out_size, void* d_ws, size_t ws_size,
                              hipStream_t stream)
{
    const float* x      = (const float*)d_in[0];
    const int*   ei     = (const int*)d_in[1];
    const float* W1a    = (const float*)d_in[2];
    const float* b1a    = (const float*)d_in[3];
    const float* W1b    = (const float*)d_in[4];
    const float* b1b    = (const float*)d_in[5];
    const float* eps1   = (const float*)d_in[6];
    const float* gamma1 = (const float*)d_in[7];
    const float* beta1  = (const float*)d_in[8];
    const float* W2a    = (const float*)d_in[9];
    const float* b2a    = (const float*)d_in[10];
    const float* W2b    = (const float*)d_in[11];
    const float* b2b    = (const float*)d_in[12];
    const float* eps2   = (const float*)d_in[13];
    const float* gamma2 = (const float*)d_in[14];
    const float* beta2  = (const float*)d_in[15];
    const float* Wout   = (const float*)d_in[16];
    const float* ltau   = (const float*)d_in[17];

    const size_t NB = (size_t)NNODES * HD;
    float* B0 = (float*)d_ws;        // gather output H0
    float* B1 = B0 + NB;             // pre-BN hidden h
    float* B2 = B1 + NB;             // MLP mid
    float* ST = B2 + NB;             // stats (1024 floats)
    float* sum1 = ST, *sq1 = ST + 128, *sum2 = ST + 256, *sq2 = ST + 384;
    float* scale1 = ST + 512, *shift1 = ST + 640, *scale2 = ST + 768, *shift2 = ST + 896;

    int* I0        = (int*)(ST + 1024);
    int* deg       = I0;
    int* incl      = I0 + 50048;
    int* row_start = I0 + 2 * 50048;
    int* cur       = I0 + 3 * 50048;
    int* bsum      = I0 + 4 * 50048;
    int* bscan     = bsum + 256;
    int* col       = bscan + 256;     // NEDGES ints

    const int SCAN_BLKS = (NNODES + 255) / 256;   // 196
    const int GEMM_BLKS = (NNODES + 63) / 64;     // 782

    hipMemsetAsync(ST, 0, 512 * sizeof(float), stream);
    hipMemsetAsync(deg, 0, NNODES * sizeof(int), stream);
    edge_hist<<<(NEDGES + 255) / 256, 256, 0, stream>>>(ei, deg);
    scan_a<<<SCAN_BLKS, 256, 0, stream>>>(deg, incl, bsum);
    scan_b<<<1, 256, 0, stream>>>(bsum, bscan, SCAN_BLKS);
    scan_c<<<SCAN_BLKS, 256, 0, stream>>>(deg, incl, bscan, row_start, cur);
    edge_fill<<<(NEDGES + 255) / 256, 256, 0, stream>>>(ei, cur, col);

    // ---- layer 1
    gin_gather<false><<<NNODES / 8, 256, 0, stream>>>(
        x, col, row_start, cur, eps1, nullptr, nullptr, B0);
    gemm128<true,  false><<<GEMM_BLKS, 256, 0, stream>>>(
        B0, W1a, b1a, B2, nullptr, nullptr);
    gemm128<false, true ><<<GEMM_BLKS, 256, 0, stream>>>(
        B2, W1b, b1b, B1, sum1, sq1);
    bn_prep<<<1, 128, 0, stream>>>(sum1, sq1, gamma1, beta1, scale1, shift1);

    // ---- layer 2 (BN1+ReLU fused into gather reads)
    gin_gather<true><<<NNODES / 8, 256, 0, stream>>>(
        B1, col, row_start, cur, eps2, scale1, shift1, B0);
    gemm128<true,  false><<<GEMM_BLKS, 256, 0, stream>>>(
        B0, W2a, b2a, B2, nullptr, nullptr);
    gemm128<false, true ><<<GEMM_BLKS, 256, 0, stream>>>(
        B2, W2b, b2b, B1, sum2, sq2);
    bn_prep<<<1, 128, 0, stream>>>(sum2, sq2, gamma2, beta2, scale2, shift2);

    // ---- projection + softmax (BN2+ReLU fused on load)
    out_proj_softmax<<<NNODES / 16, 256, 0, stream>>>(
        B1, Wout, scale2, shift2, ltau,
        (float*)d_out, (float*)d_out + (size_t)NNODES * KOUT);
}

// Round 6
// 461.256 us; speedup vs baseline: 6.8620x; 1.1151x over previous
//
#include <hip/hip_runtime.h>
#include <hip/hip_bf16.h>

// GIN 2-layer + BN + softmax pipeline for MI355X. All tensors fp32; edges int32.
// R6: gathers read bf16 side-copies (halve random-read bytes); edge_fill does
// 8 dst-range passes so col[] writes cluster into L2-resident windows.
//
// Workspace aliasing timeline (B0/B1/B2 = 25.6 MB fp32 each):
//   to_bf16:  xb=(u16*)B2  <- x
//   gather1:  reads xb(B2) -> writes B0
//   gemm1:    reads B0     -> writes B2   (kills xb, OK)
//   gemm2s:   reads B2     -> writes B1 (h1 fp32) + hb=(u16*)B0 (h1 bf16)
//   gather2:  reads hb(B0) -> writes B2
//   gemm3:    reads B2     -> writes B0   (kills hb, OK)
//   gemm4s:   reads B0     -> writes B1 (h2, kills h1, OK)
//   out_proj: reads B1

#define NNODES 50000
#define NEDGES 800000
#define HD 128
#define KOUT 64

__device__ __forceinline__ unsigned short f2bf(float f) {   // RNE bf16
    unsigned u = __float_as_uint(f);
    u += 0x7fffu + ((u >> 16) & 1u);
    return (unsigned short)(u >> 16);
}
__device__ __forceinline__ float4 bf4_to_f4(ushort4 u) {
    float4 v;
    v.x = __uint_as_float((unsigned)u.x << 16);
    v.y = __uint_as_float((unsigned)u.y << 16);
    v.z = __uint_as_float((unsigned)u.z << 16);
    v.w = __uint_as_float((unsigned)u.w << 16);
    return v;
}

// ================= fp32 -> bf16 copy =================
__global__ __launch_bounds__(256) void to_bf16(
    const float* __restrict__ in, unsigned short* __restrict__ out)
{
    int i = blockIdx.x * 256 + threadIdx.x;     // float4 index
    float4 v = ((const float4*)in)[i];
    ushort4 o;
    o.x = f2bf(v.x); o.y = f2bf(v.y); o.z = f2bf(v.z); o.w = f2bf(v.w);
    ((ushort4*)out)[i] = o;
}

// ================= CSR build =================
__global__ __launch_bounds__(256) void edge_hist(
    const int* __restrict__ ei, int* __restrict__ deg)
{
    int e = blockIdx.x * 256 + threadIdx.x;
    if (e < NEDGES) atomicAdd(&deg[ei[NEDGES + e]], 1);
}

__global__ __launch_bounds__(256) void scan_a(
    const int* __restrict__ deg, int* __restrict__ incl, int* __restrict__ bsum)
{
    __shared__ int s[256];
    int t = threadIdx.x, idx = blockIdx.x * 256 + t;
    int v = (idx < NNODES) ? deg[idx] : 0;
    s[t] = v; __syncthreads();
    #pragma unroll
    for (int off = 1; off < 256; off <<= 1) {
        int tmp = (t >= off) ? s[t - off] : 0;
        __syncthreads();
        s[t] += tmp;
        __syncthreads();
    }
    if (idx < NNODES) incl[idx] = s[t];
    if (t == 255) bsum[blockIdx.x] = s[255];
}

__global__ __launch_bounds__(256) void scan_b(
    const int* __restrict__ bsum, int* __restrict__ bscan, int nblk)
{
    __shared__ int s[256];
    int t = threadIdx.x;
    s[t] = (t < nblk) ? bsum[t] : 0; __syncthreads();
    #pragma unroll
    for (int off = 1; off < 256; off <<= 1) {
        int tmp = (t >= off) ? s[t - off] : 0;
        __syncthreads();
        s[t] += tmp;
        __syncthreads();
    }
    bscan[t] = s[t];
}

__global__ __launch_bounds__(256) void scan_c(
    const int* __restrict__ deg, const int* __restrict__ incl,
    const int* __restrict__ bscan,
    int* __restrict__ row_start, int* __restrict__ cur)
{
    int b = blockIdx.x, t = threadIdx.x, idx = b * 256 + t;
    if (idx >= NNODES) return;
    int off = (b > 0) ? bscan[b - 1] : 0;
    int ex = incl[idx] - deg[idx] + off;
    row_start[idx] = ex;
    cur[idx] = ex;
}

// 8 dst-range passes: all 3125 blocks are co-resident, so pass p's col writes
// cluster into a ~E/8*4B window -> L2 collects full lines before writeback.
__global__ __launch_bounds__(256) void edge_fill(
    const int* __restrict__ ei, int* __restrict__ cur, int* __restrict__ col)
{
    int e = blockIdx.x * 256 + threadIdx.x;
    int src = ei[e];
    int dst = ei[NEDGES + e];
    #pragma unroll 1
    for (int p = 0; p < 8; ++p) {
        if ((dst >> 13) + ((dst & 8191) >= 6250 ? 1 : 0) == p || // never true pad-free path below
            (dst / 6250) == p) {
            // (dst/6250)==p is the real test; first clause folded out by compiler
        }
        if (dst / 6250 == p) {
            int pos = atomicAdd(&cur[dst], 1);
            col[pos] = src;
        }
    }
}

// ========== gather (bf16 rows): H0[i] = (1+eps)*f(Xb[i]) + sum_j f(Xb[col[j]])
// f = BN-scale/shift + ReLU when BN=true. 32 lanes/node, ushort4(8B)/lane.
template<bool BN>
__global__ __launch_bounds__(256) void gin_gather_b(
    const unsigned short* __restrict__ Xb, const int* __restrict__ col,
    const int* __restrict__ rs, const int* __restrict__ re,
    const float* __restrict__ eps,
    const float* __restrict__ scale, const float* __restrict__ shift,
    float* __restrict__ H0)
{
    int t = threadIdx.x;
    int node = blockIdx.x * 8 + (t >> 5);
    int lane = t & 31;
    const ushort4* X4 = (const ushort4*)Xb;
    float alpha = 1.f + eps[0];

    float4 sc, sh;
    if (BN) { sc = ((const float4*)scale)[lane]; sh = ((const float4*)shift)[lane]; }

    float4 xi = bf4_to_f4(X4[(long)node * 32 + lane]);
    if (BN) {
        xi.x = fmaxf(fmaf(xi.x, sc.x, sh.x), 0.f);
        xi.y = fmaxf(fmaf(xi.y, sc.y, sh.y), 0.f);
        xi.z = fmaxf(fmaf(xi.z, sc.z, sh.z), 0.f);
        xi.w = fmaxf(fmaf(xi.w, sc.w, sh.w), 0.f);
    }
    float4 acc;
    acc.x = alpha * xi.x; acc.y = alpha * xi.y;
    acc.z = alpha * xi.z; acc.w = alpha * xi.w;

    int j = rs[node], end = re[node];
    for (; j + 3 < end; j += 4) {
        ushort4 u0 = X4[(long)col[j]     * 32 + lane];
        ushort4 u1 = X4[(long)col[j + 1] * 32 + lane];
        ushort4 u2 = X4[(long)col[j + 2] * 32 + lane];
        ushort4 u3 = X4[(long)col[j + 3] * 32 + lane];
        float4 a0 = bf4_to_f4(u0), a1 = bf4_to_f4(u1);
        float4 a2 = bf4_to_f4(u2), a3 = bf4_to_f4(u3);
        if (BN) {
            a0.x = fmaxf(fmaf(a0.x, sc.x, sh.x), 0.f);
            a0.y = fmaxf(fmaf(a0.y, sc.y, sh.y), 0.f);
            a0.z = fmaxf(fmaf(a0.z, sc.z, sh.z), 0.f);
            a0.w = fmaxf(fmaf(a0.w, sc.w, sh.w), 0.f);
            a1.x = fmaxf(fmaf(a1.x, sc.x, sh.x), 0.f);
            a1.y = fmaxf(fmaf(a1.y, sc.y, sh.y), 0.f);
            a1.z = fmaxf(fmaf(a1.z, sc.z, sh.z), 0.f);
            a1.w = fmaxf(fmaf(a1.w, sc.w, sh.w), 0.f);
            a2.x = fmaxf(fmaf(a2.x, sc.x, sh.x), 0.f);
            a2.y = fmaxf(fmaf(a2.y, sc.y, sh.y), 0.f);
            a2.z = fmaxf(fmaf(a2.z, sc.z, sh.z), 0.f);
            a2.w = fmaxf(fmaf(a2.w, sc.w, sh.w), 0.f);
            a3.x = fmaxf(fmaf(a3.x, sc.x, sh.x), 0.f);
            a3.y = fmaxf(fmaf(a3.y, sc.y, sh.y), 0.f);
            a3.z = fmaxf(fmaf(a3.z, sc.z, sh.z), 0.f);
            a3.w = fmaxf(fmaf(a3.w, sc.w, sh.w), 0.f);
        }
        acc.x += (a0.x + a1.x) + (a2.x + a3.x);
        acc.y += (a0.y + a1.y) + (a2.y + a3.y);
        acc.z += (a0.z + a1.z) + (a2.z + a3.z);
        acc.w += (a0.w + a1.w) + (a2.w + a3.w);
    }
    for (; j < end; ++j) {
        float4 a = bf4_to_f4(X4[(long)col[j] * 32 + lane]);
        if (BN) {
            a.x = fmaxf(fmaf(a.x, sc.x, sh.x), 0.f);
            a.y = fmaxf(fmaf(a.y, sc.y, sh.y), 0.f);
            a.z = fmaxf(fmaf(a.z, sc.z, sh.z), 0.f);
            a.w = fmaxf(fmaf(a.w, sc.w, sh.w), 0.f);
        }
        acc.x += a.x; acc.y += a.y; acc.z += a.z; acc.w += a.w;
    }
    ((float4*)H0)[(long)node * 32 + lane] = acc;
}

// ========== GEMM: C[M,128] = A @ W[128,128] + b; 64 rows/block, 8x4/thread.
// STATS also emits per-column sum/sumsq atomics; Hb (optional) = bf16 copy of C.
template<bool RELU, bool STATS>
__global__ __launch_bounds__(256) void gemm128(
    const float* __restrict__ X,
    const float* __restrict__ W, const float* __restrict__ bias,
    float* __restrict__ C, float* __restrict__ out_sum, float* __restrict__ out_sq,
    unsigned short* __restrict__ Hb)
{
    __shared__ float As[64][132];
    const int t = threadIdx.x;
    const int row0 = blockIdx.x * 64;

    #pragma unroll
    for (int i = 0; i < 8; ++i) {
        int idx = t + i * 256;
        int r = idx >> 5, c4 = idx & 31;
        float4 v = make_float4(0.f, 0.f, 0.f, 0.f);
        if (row0 + r < NNODES)
            v = *(const float4*)(X + (long)(row0 + r) * HD + c4 * 4);
        *(float4*)&As[r][c4 * 4] = v;
    }
    __syncthreads();

    const int c0 = (t & 31) * 4;
    const int r0 = (t >> 5) * 8;
    float acc[8][4] = {};
    #pragma unroll 4
    for (int k = 0; k < HD; ++k) {
        float4 w = *(const float4*)(W + k * HD + c0);
        #pragma unroll
        for (int j = 0; j < 8; ++j) {
            float a = As[r0 + j][k];
            acc[j][0] = fmaf(a, w.x, acc[j][0]);
            acc[j][1] = fmaf(a, w.y, acc[j][1]);
            acc[j][2] = fmaf(a, w.z, acc[j][2]);
            acc[j][3] = fmaf(a, w.w, acc[j][3]);
        }
    }

    float4 bb = *(const float4*)(bias + c0);
    float lsum[4] = {}, lsq[4] = {};
    #pragma unroll
    for (int j = 0; j < 8; ++j) {
        int row = row0 + r0 + j;
        float4 v;
        v.x = acc[j][0] + bb.x; v.y = acc[j][1] + bb.y;
        v.z = acc[j][2] + bb.z; v.w = acc[j][3] + bb.w;
        if (RELU) {
            v.x = fmaxf(v.x, 0.f); v.y = fmaxf(v.y, 0.f);
            v.z = fmaxf(v.z, 0.f); v.w = fmaxf(v.w, 0.f);
        }
        if (row < NNODES) {
            *(float4*)(C + (long)row * HD + c0) = v;
            if (Hb) {
                ushort4 o;
                o.x = f2bf(v.x); o.y = f2bf(v.y);
                o.z = f2bf(v.z); o.w = f2bf(v.w);
                ((ushort4*)Hb)[(long)row * 32 + (c0 >> 2)] = o;
            }
            if (STATS) {
                lsum[0] += v.x; lsum[1] += v.y; lsum[2] += v.z; lsum[3] += v.w;
                lsq[0] = fmaf(v.x, v.x, lsq[0]);
                lsq[1] = fmaf(v.y, v.y, lsq[1]);
                lsq[2] = fmaf(v.z, v.z, lsq[2]);
                lsq[3] = fmaf(v.w, v.w, lsq[3]);
            }
        }
    }
    if (STATS) {
        __shared__ float redS[8][128];
        __shared__ float redQ[8][128];
        const int rg = t >> 5;
        #pragma unroll
        for (int j = 0; j < 4; ++j) {
            redS[rg][c0 + j] = lsum[j];
            redQ[rg][c0 + j] = lsq[j];
        }
        __syncthreads();
        if (t < 128) {
            float s = 0.f, q = 0.f;
            #pragma unroll
            for (int g = 0; g < 8; ++g) { s += redS[g][t]; q += redQ[g][t]; }
            atomicAdd(&out_sum[t], s);
            atomicAdd(&out_sq[t],  q);
        }
    }
}

// ================= BN fold =================
__global__ void bn_prep(const float* __restrict__ ssum, const float* __restrict__ ssq,
                        const float* __restrict__ gamma, const float* __restrict__ beta,
                        float* __restrict__ scale, float* __restrict__ shift)
{
    int c = threadIdx.x;
    const float invN = 1.0f / (float)NNODES;
    float m = ssum[c] * invN;
    float var = fmaf(-m, m, ssq[c] * invN);
    float rs = rsqrtf(var + 1e-5f);
    float sc = gamma[c] * rs;
    scale[c] = sc;
    shift[c] = beta[c] - m * sc;
}

// ========== projection + softmax, BN2+ReLU fused on load ==========
__global__ __launch_bounds__(256) void out_proj_softmax(
    const float* __restrict__ H, const float* __restrict__ Wout,
    const float* __restrict__ scale, const float* __restrict__ shift,
    const float* __restrict__ log_tau,
    float* __restrict__ outS, float* __restrict__ outL)
{
    __shared__ float As[HD][20];
    const int t = threadIdx.x;
    const long row0 = (long)blockIdx.x * 16;

    #pragma unroll
    for (int i = 0; i < 8; ++i) {
        int idx = t + i * 256;
        int r = idx >> 7, cc = idx & 127;
        float v = H[(row0 + r) * HD + cc];
        As[cc][r] = fmaxf(fmaf(v, scale[cc], shift[cc]), 0.f);
    }
    __syncthreads();

    const int c = t & 63;
    const int g = t >> 6;
    float acc[4] = {};
    #pragma unroll 4
    for (int k = 0; k < HD; ++k) {
        float w = Wout[k * KOUT + c];
        float4 a = *(const float4*)&As[k][g * 4];
        acc[0] = fmaf(a.x, w, acc[0]);
        acc[1] = fmaf(a.y, w, acc[1]);
        acc[2] = fmaf(a.z, w, acc[2]);
        acc[3] = fmaf(a.w, w, acc[3]);
    }

    float inv_tau = __expf(-log_tau[0]);
    #pragma unroll
    for (int i = 0; i < 4; ++i) {
        float z = acc[i] * inv_tau;
        float m = z;
        #pragma unroll
        for (int o = 32; o > 0; o >>= 1) m = fmaxf(m, __shfl_xor(m, o));
        float e = __expf(z - m);
        float s = e;
        #pragma unroll
        for (int o = 32; o > 0; o >>= 1) s += __shfl_xor(s, o);
        long oi = (row0 + g * 4 + i) * KOUT + c;
        outS[oi] = e / s;
        outL[oi] = acc[i];
    }
}

extern "C" void kernel_launch(void* const* d_in, const int* in_sizes, int n_in,
                              void* d_out, int out_size, void* d_ws, size_t ws_size,
                              hipStream_t stream)
{
    const float* x      = (const float*)d_in[0];
    const int*   ei     = (const int*)d_in[1];
    const float* W1a    = (const float*)d_in[2];
    const float* b1a    = (const float*)d_in[3];
    const float* W1b    = (const float*)d_in[4];
    const float* b1b    = (const float*)d_in[5];
    const float* eps1   = (const float*)d_in[6];
    const float* gamma1 = (const float*)d_in[7];
    const float* beta1  = (const float*)d_in[8];
    const float* W2a    = (const float*)d_in[9];
    const float* b2a    = (const float*)d_in[10];
    const float* W2b    = (const float*)d_in[11];
    const float* b2b    = (const float*)d_in[12];
    const float* eps2   = (const float*)d_in[13];
    const float* gamma2 = (const float*)d_in[14];
    const float* beta2  = (const float*)d_in[15];
    const float* Wout   = (const float*)d_in[16];
    const float* ltau   = (const float*)d_in[17];

    const size_t NB = (size_t)NNODES * HD;
    float* B0 = (float*)d_ws;
    float* B1 = B0 + NB;
    float* B2 = B1 + NB;
    float* ST = B2 + NB;             // stats (1024 floats)
    float* sum1 = ST, *sq1 = ST + 128, *sum2 = ST + 256, *sq2 = ST + 384;
    float* scale1 = ST + 512, *shift1 = ST + 640, *scale2 = ST + 768, *shift2 = ST + 896;

    unsigned short* xb = (unsigned short*)B2;   // bf16 x during CSR+gather1
    unsigned short* hb = (unsigned short*)B0;   // bf16 h1 during gather2

    int* I0        = (int*)(ST + 1024);
    int* deg       = I0;
    int* incl      = I0 + 50048;
    int* row_start = I0 + 2 * 50048;
    int* cur       = I0 + 3 * 50048;
    int* bsum      = I0 + 4 * 50048;
    int* bscan     = bsum + 256;
    int* col       = bscan + 256;     // NEDGES ints

    const int SCAN_BLKS = (NNODES + 255) / 256;   // 196
    const int GEMM_BLKS = (NNODES + 63) / 64;     // 782

    hipMemsetAsync(ST, 0, 512 * sizeof(float), stream);
    hipMemsetAsync(deg, 0, NNODES * sizeof(int), stream);
    to_bf16<<<NNODES * HD / 1024, 256, 0, stream>>>(x, xb);
    edge_hist<<<(NEDGES + 255) / 256, 256, 0, stream>>>(ei, deg);
    scan_a<<<SCAN_BLKS, 256, 0, stream>>>(deg, incl, bsum);
    scan_b<<<1, 256, 0, stream>>>(bsum, bscan, SCAN_BLKS);
    scan_c<<<SCAN_BLKS, 256, 0, stream>>>(deg, incl, bscan, row_start, cur);
    edge_fill<<<NEDGES / 256, 256, 0, stream>>>(ei, cur, col);

    // ---- layer 1
    gin_gather_b<false><<<NNODES / 8, 256, 0, stream>>>(
        xb, col, row_start, cur, eps1, nullptr, nullptr, B0);
    gemm128<true,  false><<<GEMM_BLKS, 256, 0, stream>>>(
        B0, W1a, b1a, B2, nullptr, nullptr, nullptr);
    gemm128<false, true ><<<GEMM_BLKS, 256, 0, stream>>>(
        B2, W1b, b1b, B1, sum1, sq1, hb);
    bn_prep<<<1, 128, 0, stream>>>(sum1, sq1, gamma1, beta1, scale1, shift1);

    // ---- layer 2 (BN1+ReLU fused into gather reads, from bf16 h1)
    gin_gather_b<true><<<NNODES / 8, 256, 0, stream>>>(
        hb, col, row_start, cur, eps2, scale1, shift1, B2);
    gemm128<true,  false><<<GEMM_BLKS, 256, 0, stream>>>(
        B2, W2a, b2a, B0, nullptr, nullptr, nullptr);
    gemm128<false, true ><<<GEMM_BLKS, 256, 0, stream>>>(
        B0, W2b, b2b, B1, sum2, sq2, nullptr);
    bn_prep<<<1, 128, 0, stream>>>(sum2, sq2, gamma2, beta2, scale2, shift2);

    // ---- projection + softmax (BN2+ReLU fused on load)
    out_proj_softmax<<<NNODES / 16, 256, 0, stream>>>(
        B1, Wout, scale2, shift2, ltau,
        (float*)d_out, (float*)d_out + (size_t)NNODES * KOUT);
}